// Round 14
// baseline (34.184 us; speedup 1.0000x reference)
//
#include <hip/hip_runtime.h>
#include <hip/hip_fp16.h>

constexpr int H  = 8;
constexpr int T  = 2048;
constexpr int DH = 64;
constexpr int D  = 64;
constexpr int NKV = H * T * DH;   // 1M elements per tensor

typedef _Float16 half2v __attribute__((ext_vector_type(2)));

#if defined(__has_builtin)
#if __has_builtin(__builtin_amdgcn_fdot2)
#define HAVE_FDOT2 1
#endif
#if __has_builtin(__builtin_amdgcn_permlane32_swap)
#define HAVE_PL32 1
#endif
#if __has_builtin(__builtin_amdgcn_permlane16_swap)
#define HAVE_PL16 1
#endif
#if __has_builtin(__builtin_amdgcn_mbcnt_lo)
#define HAVE_MBCNT 1
#endif
#endif

__device__ __forceinline__ float dot2acc(half2v a, half2v b, float c) {
#ifdef HAVE_FDOT2
    return __builtin_amdgcn_fdot2(a, b, c, false);
#else
    return c + (float)a.x * (float)b.x + (float)a.y * (float)b.y;
#endif
}

__device__ __forceinline__ half2v h2bits(int b) { return __builtin_bit_cast(half2v, b); }

__device__ __forceinline__ half2v f2h2(float x, float y) {
    __half2 h = __float22half2_rn(make_float2(x, y));
    return __builtin_bit_cast(half2v, h);
}

// ---- DPP cross-lane (VALU pipe) ----
template<int CTRL>
__device__ __forceinline__ float dpp_mov_f(float x) {
    int yi = __builtin_amdgcn_update_dpp(0, __builtin_bit_cast(int, x),
                                         CTRL, 0xF, 0xF, true);
    return __builtin_bit_cast(float, yi);
}
template<int CTRL>
__device__ __forceinline__ float dpp_add_f(float x) { return x + dpp_mov_f<CTRL>(x); }
template<int CTRL>
__device__ __forceinline__ float dpp_max_f(float x) { return fmaxf(x, dpp_mov_f<CTRL>(x)); }

// ---- permlane swap helpers (VALU pipe) ----
__device__ __forceinline__ float xor32add_f(float x) {
#ifdef HAVE_PL32
    unsigned u = __builtin_bit_cast(unsigned, x);
    auto r = __builtin_amdgcn_permlane32_swap(u, u, false, false);
    return __builtin_bit_cast(float, (unsigned)r[0]) + __builtin_bit_cast(float, (unsigned)r[1]);
#else
    return x + __shfl_xor(x, 32);
#endif
}
__device__ __forceinline__ float xor32max_f(float x) {
#ifdef HAVE_PL32
    unsigned u = __builtin_bit_cast(unsigned, x);
    auto r = __builtin_amdgcn_permlane32_swap(u, u, false, false);
    return fmaxf(__builtin_bit_cast(float, (unsigned)r[0]), __builtin_bit_cast(float, (unsigned)r[1]));
#else
    return fmaxf(x, __shfl_xor(x, 32));
#endif
}
__device__ __forceinline__ float xor16add_f(float x) {
#ifdef HAVE_PL16
    unsigned u = __builtin_bit_cast(unsigned, x);
    auto r = __builtin_amdgcn_permlane16_swap(u, u, false, false);
    return __builtin_bit_cast(float, (unsigned)r[0]) + __builtin_bit_cast(float, (unsigned)r[1]);
#else
    return x + __shfl_xor(x, 16);
#endif
}
__device__ __forceinline__ float xor16max_f(float x) {
#ifdef HAVE_PL16
    unsigned u = __builtin_bit_cast(unsigned, x);
    auto r = __builtin_amdgcn_permlane16_swap(u, u, false, false);
    return fmaxf(__builtin_bit_cast(float, (unsigned)r[0]), __builtin_bit_cast(float, (unsigned)r[1]));
#else
    return fmaxf(x, __shfl_xor(x, 16));
#endif
}
__device__ __forceinline__ half2v xor32add_h2(half2v x) {
#ifdef HAVE_PL32
    unsigned u = __builtin_bit_cast(unsigned, x);
    auto r = __builtin_amdgcn_permlane32_swap(u, u, false, false);
    return h2bits((int)r[0]) + h2bits((int)r[1]);
#else
    return x + h2bits(__shfl_xor(__builtin_bit_cast(int, x), 32));
#endif
}
__device__ __forceinline__ half2v xor16add_h2(half2v x) {
#ifdef HAVE_PL16
    unsigned u = __builtin_bit_cast(unsigned, x);
    auto r = __builtin_amdgcn_permlane16_swap(u, u, false, false);
    return h2bits((int)r[0]) + h2bits((int)r[1]);
#else
    return x + h2bits(__shfl_xor(__builtin_bit_cast(int, x), 16));
#endif
}
__device__ __forceinline__ half2v xor8add_h2(half2v x) {
    return x + h2bits(__shfl_xor(__builtin_bit_cast(int, x), 8));
}

// ---- prepass: f32 -> f16 for k and v only (12 MB streamed) ----
__global__ __launch_bounds__(256) void cvt_f32_f16(
    const float* __restrict__ k, const float* __restrict__ v,
    __half* __restrict__ kh, __half* __restrict__ vh)
{
    const int i = (blockIdx.x * 256 + threadIdx.x) * 8;
    const float* src = (blockIdx.y == 0) ? k : v;
    __half*      dst = (blockIdx.y == 0) ? kh : vh;
    const float4 a = *reinterpret_cast<const float4*>(src + i);
    const float4 b = *reinterpret_cast<const float4*>(src + i + 4);
    __half2 hh[4];
    hh[0] = __float22half2_rn(make_float2(a.x, a.y));
    hh[1] = __float22half2_rn(make_float2(a.z, a.w));
    hh[2] = __float22half2_rn(make_float2(b.x, b.y));
    hh[3] = __float22half2_rn(make_float2(b.z, b.w));
    *reinterpret_cast<float4*>(dst + i) = *reinterpret_cast<const float4*>(hh);
}

// ---- main: COMPACTED fp16 gathers ----
// Valid neighbors (idx<=t, avg ~50%) are stream-compacted per wave via
// ballot + mbcnt prefix + one exec-masked LDS scatter. Gather rounds then
// cover only ceil(total/8) slots of 8 rows each; remaining rounds are
// skipped by WAVE-UNIFORM branches (whole VMEM instructions never issue --
// this is the lever R13's per-lane exec-masking missed). Partial-round
// slots clamp to the last valid entry; their weights are forced 0 by the
// c<total test. All-masked query -> every round skipped -> exact 0 output.
__global__ __launch_bounds__(256) void wayfinder_attn_f16(
    const float* __restrict__ q,
    const __half* __restrict__ kh,
    const __half* __restrict__ vh,
    const float* __restrict__ eb,
    const int*   __restrict__ nidx,
    const int*   __restrict__ etyp,
    float* __restrict__ out)
{
    __shared__ int cbuf[4][64];   // per-wave compacted {idx | et<<11}

    const int wave = threadIdx.x >> 6;
    const int lane = threadIdx.x & 63;
    const int bid  = blockIdx.x;
    const int work = ((bid & 7) << 9) | (bid >> 3);   // XCD i <-> head i
    const int flat = (work << 2) + wave;              // h*T + t
    const int h    = flat >> 11;
    const int t    = flat & (T - 1);
    const int grp  = lane >> 3;
    const int sub  = lane & 7;

    const long long rowoff = (long long)flat * DH;

    // metadata: coalesced at lane = n
    const int idx = nidx[(long long)flat * D + lane];
    const int et  = etyp[(long long)flat * D + lane];
    const bool mk = (unsigned)idx <= (unsigned)t;

    // wave-level compaction
    const unsigned long long M = __ballot(mk);
    const int total = __builtin_amdgcn_readfirstlane((int)__popcll(M));
#ifdef HAVE_MBCNT
    const int pos = __builtin_amdgcn_mbcnt_hi((unsigned)(M >> 32),
                    __builtin_amdgcn_mbcnt_lo((unsigned)M, 0u));
#else
    const int pos = (int)__popcll(M & ((1ull << lane) - 1ull));
#endif
    if (mk) cbuf[wave][pos] = idx | (et << 11);

    // q fragment: channels sub*8 .. sub*8+7, f32 load then in-register fp16
    const float4 qa = *reinterpret_cast<const float4*>(q + rowoff + sub * 8);
    const float4 qb = *reinterpret_cast<const float4*>(q + rowoff + sub * 8 + 4);

    const __half* khead = kh + (long long)h * T * DH;
    const __half* vhead = vh + (long long)h * T * DH;

    half2v qp[4];
    qp[0] = f2h2(qa.x, qa.y);
    qp[1] = f2h2(qa.z, qa.w);
    qp[2] = f2h2(qb.x, qb.y);
    qp[3] = f2h2(qb.z, qb.w);

    // Pass 1 (guarded, wave-uniform): read compact entries, issue gathers
    int packed[8] = {0, 0, 0, 0, 0, 0, 0, 0};
    float4 kf[8], vf[8];
    #pragma unroll
    for (int j = 0; j < 8; ++j) {
        if (total > j * 8) {
            const int c  = min(j * 8 + grp, total - 1);
            const int pk = cbuf[wave][c];
            packed[j] = pk;
            const long long ro = (long long)(pk & 0x7FF) * DH + sub * 8;
            kf[j] = *reinterpret_cast<const float4*>(khead + ro);
            vf[j] = *reinterpret_cast<const float4*>(vhead + ro);
        }
    }

    const float4 ebv = *reinterpret_cast<const float4*>(eb);

    // Pass 2 (guarded): QK fdot2 + 3 DPP reduce levels
    float sc[8] = {0.f, 0.f, 0.f, 0.f, 0.f, 0.f, 0.f, 0.f};
    #pragma unroll
    for (int j = 0; j < 8; ++j) {
        if (total > j * 8) {
            const half2v* kp = reinterpret_cast<const half2v*>(&kf[j]);
            float p = dot2acc(qp[0], kp[0],
                      dot2acc(qp[1], kp[1],
                      dot2acc(qp[2], kp[2],
                      dot2acc(qp[3], kp[3], 0.0f))));
            p = dpp_add_f<0xB1>(p);    // xor1 (exact)
            p = dpp_add_f<0x4E>(p);    // xor2 (exact)
            p = dpp_add_f<0x141>(p);   // cross-quad (quad-uniform by now)
            sc[j] = p;
        }
    }

    // softmax over compact slots (valid = c < total), group-local + permlane
    float masked[8];
    float mx = -1e30f;
    #pragma unroll
    for (int j = 0; j < 8; ++j) {
        const bool valid = (j * 8 + grp) < total;
        const int  etj   = packed[j] >> 11;
        const float bias = (etj == 1) ? ebv.x : (etj == 2) ? ebv.y :
                           (etj == 3) ? ebv.z : (etj == 4) ? ebv.w : 0.0f;
        masked[j] = valid ? fmaf(sc[j], 0.125f, bias) : -1e30f;
        mx = fmaxf(mx, masked[j]);
    }
    mx = dpp_max_f<0x140>(mx);
    mx = xor16max_f(mx);
    mx = xor32max_f(mx);

    float e[8];
    float sum = 0.0f;
    #pragma unroll
    for (int j = 0; j < 8; ++j) {
        const bool valid = (j * 8 + grp) < total;
        e[j] = valid ? __expf(masked[j] - mx) : 0.0f;
        sum += e[j];
    }
    sum = dpp_add_f<0x140>(sum);
    sum = xor16add_f(sum);
    sum = xor32add_f(sum);
    const float rden = 1.0f / fmaxf(sum, 1e-9f);

    // Pass 3 (guarded): PV accumulate (clamped slots have e=0)
    float acc[8] = {0.f, 0.f, 0.f, 0.f, 0.f, 0.f, 0.f, 0.f};
    #pragma unroll
    for (int j = 0; j < 8; ++j) {
        if (total > j * 8) {
            const float w = e[j] * rden;
            const half2v* vp = reinterpret_cast<const half2v*>(&vf[j]);
            acc[0] += w * (float)vp[0].x;  acc[1] += w * (float)vp[0].y;
            acc[2] += w * (float)vp[1].x;  acc[3] += w * (float)vp[1].y;
            acc[4] += w * (float)vp[2].x;  acc[5] += w * (float)vp[2].y;
            acc[6] += w * (float)vp[3].x;  acc[7] += w * (float)vp[3].y;
        }
    }

    // cross-group reduce on packed halves: exact xor8 (DS) then permlane
    half2v h0 = f2h2(acc[0], acc[1]);
    half2v h1 = f2h2(acc[2], acc[3]);
    half2v h2 = f2h2(acc[4], acc[5]);
    half2v h3 = f2h2(acc[6], acc[7]);
    h0 = xor8add_h2(h0);  h1 = xor8add_h2(h1);
    h2 = xor8add_h2(h2);  h3 = xor8add_h2(h3);
    h0 = xor16add_h2(h0); h1 = xor16add_h2(h1);
    h2 = xor16add_h2(h2); h3 = xor16add_h2(h3);
    h0 = xor32add_h2(h0); h1 = xor32add_h2(h1);
    h2 = xor32add_h2(h2); h3 = xor32add_h2(h3);

    if (lane < 16) {
        const int s8   = (lane & 7) * 8;
        const int half = lane >> 3;
        const float4 o = half
            ? make_float4((float)h2.x, (float)h2.y, (float)h3.x, (float)h3.y)
            : make_float4((float)h0.x, (float)h0.y, (float)h1.x, (float)h1.y);
        *reinterpret_cast<float4*>(out + rowoff + s8 + half * 4) = o;
    }
}

// ---- fallback: f32 kernel (used if ws too small) ----
__global__ __launch_bounds__(256) void wayfinder_attn_f32(
    const float* __restrict__ q, const float* __restrict__ k,
    const float* __restrict__ v, const float* __restrict__ eb,
    const int* __restrict__ nidx, const int* __restrict__ etyp,
    float* __restrict__ out)
{
    const int wave = threadIdx.x >> 6;
    const int lane = threadIdx.x & 63;
    const int flat = (blockIdx.x << 2) + wave;
    const int h    = flat >> 11;
    const int t    = flat & (T - 1);
    const int grp  = lane >> 4;
    const int sub  = lane & 15;

    __shared__ int    sidx[4][64];
    __shared__ float  ssc [4][64];
    __shared__ float2 swv [4][64];

    const long long rowoff = (long long)flat * DH;
    const long long noff = (long long)flat * D + lane;
    const int  idx = nidx[noff];
    const int  et  = etyp[noff];
    const int  s   = min(max(idx, 0), T - 1);
    const bool msk = (idx >= 0) && (idx <= t);
    const float4 ebv  = *reinterpret_cast<const float4*>(eb);
    const float  bias = (et == 1) ? ebv.x : (et == 2) ? ebv.y :
                        (et == 3) ? ebv.z : (et == 4) ? ebv.w : 0.0f;
    sidx[wave][lane] = s;
    const float4 qf = *reinterpret_cast<const float4*>(q + rowoff + sub * 4);
    __syncthreads();

    const float* khead = k + (long long)h * T * DH;
    #pragma unroll
    for (int i = 0; i < 16; ++i) {
        const int n  = i * 4 + grp;
        const int sn = sidx[wave][n];
        const float4 kf = *reinterpret_cast<const float4*>(khead + sn * DH + sub * 4);
        float p = qf.x * kf.x + qf.y * kf.y + qf.z * kf.z + qf.w * kf.w;
        p += __shfl_xor(p, 1);
        p += __shfl_xor(p, 2);
        p += __shfl_xor(p, 4);
        p += __shfl_xor(p, 8);
        if (sub == 0) ssc[wave][n] = p;
    }
    __syncthreads();

    const float sc     = ssc[wave][lane];
    const float masked = msk ? (sc * 0.125f + bias) : -1e30f;
    float mx = masked;
    #pragma unroll
    for (int off = 32; off > 0; off >>= 1) mx = fmaxf(mx, __shfl_xor(mx, off));
    const float e = msk ? __expf(masked - mx) : 0.0f;
    float sum = e;
    #pragma unroll
    for (int off = 32; off > 0; off >>= 1) sum += __shfl_xor(sum, off);
    const float w = e / fmaxf(sum, 1e-9f);
    swv[wave][lane] = make_float2(w, __int_as_float(s));
    __syncthreads();

    const float* vhead = v + (long long)h * T * DH;
    float4 acc = make_float4(0.f, 0.f, 0.f, 0.f);
    #pragma unroll
    for (int i = 0; i < 16; ++i) {
        const int    n  = i * 4 + grp;
        const float2 ws = swv[wave][n];
        const int    sn = __float_as_int(ws.y);
        const float4 vf = *reinterpret_cast<const float4*>(vhead + sn * DH + sub * 4);
        acc.x += ws.x * vf.x; acc.y += ws.x * vf.y;
        acc.z += ws.x * vf.z; acc.w += ws.x * vf.w;
    }
    #pragma unroll
    for (int off = 16; off <= 32; off <<= 1) {
        acc.x += __shfl_xor(acc.x, off); acc.y += __shfl_xor(acc.y, off);
        acc.z += __shfl_xor(acc.z, off); acc.w += __shfl_xor(acc.w, off);
    }
    if (lane < 16)
        *reinterpret_cast<float4*>(out + rowoff + sub * 4) = acc;
}

extern "C" void kernel_launch(void* const* d_in, const int* in_sizes, int n_in,
                              void* d_out, int out_size, void* d_ws, size_t ws_size,
                              hipStream_t stream) {
    const float* q    = (const float*)d_in[0];
    const float* k    = (const float*)d_in[1];
    const float* v    = (const float*)d_in[2];
    const float* eb   = (const float*)d_in[3];
    const int*   nidx = (const int*)d_in[4];
    const int*   etyp = (const int*)d_in[5];
    float* out = (float*)d_out;

    const size_t need = (size_t)2 * NKV * sizeof(__half);   // 4 MB
    if (ws_size >= need) {
        __half* kh = (__half*)d_ws;
        __half* vh = kh + NKV;
        dim3 cgrid(NKV / (256 * 8), 2);
        hipLaunchKernelGGL(cvt_f32_f16, cgrid, dim3(256), 0, stream, k, v, kh, vh);
        hipLaunchKernelGGL(wayfinder_attn_f16, dim3(H * T / 4), dim3(256), 0, stream,
                           q, kh, vh, eb, nidx, etyp, out);
    } else {
        hipLaunchKernelGGL(wayfinder_attn_f32, dim3(H * T / 4), dim3(256), 0, stream,
                           q, k, v, eb, nidx, etyp, out);
    }
}

// Round 15
// 25.318 us; speedup vs baseline: 1.3502x; 1.3502x over previous
//
#include <hip/hip_runtime.h>
#include <hip/hip_fp16.h>

constexpr int H  = 8;
constexpr int T  = 2048;
constexpr int DH = 64;
constexpr int D  = 64;
constexpr int NKV = H * T * DH;   // 1M elements per tensor

typedef _Float16 half2v __attribute__((ext_vector_type(2)));

#if defined(__has_builtin)
#if __has_builtin(__builtin_amdgcn_fdot2)
#define HAVE_FDOT2 1
#endif
#if __has_builtin(__builtin_amdgcn_permlane32_swap)
#define HAVE_PL32 1
#endif
#if __has_builtin(__builtin_amdgcn_permlane16_swap)
#define HAVE_PL16 1
#endif
#endif

__device__ __forceinline__ float dot2acc(half2v a, half2v b, float c) {
#ifdef HAVE_FDOT2
    return __builtin_amdgcn_fdot2(a, b, c, false);
#else
    return c + (float)a.x * (float)b.x + (float)a.y * (float)b.y;
#endif
}

__device__ __forceinline__ half2v h2bits(int b) { return __builtin_bit_cast(half2v, b); }

__device__ __forceinline__ half2v f2h2(float x, float y) {
    __half2 h = __float22half2_rn(make_float2(x, y));
    return __builtin_bit_cast(half2v, h);
}

// ---- DPP cross-lane (VALU pipe) ----
template<int CTRL>
__device__ __forceinline__ float dpp_mov_f(float x) {
    int yi = __builtin_amdgcn_update_dpp(0, __builtin_bit_cast(int, x),
                                         CTRL, 0xF, 0xF, true);
    return __builtin_bit_cast(float, yi);
}
template<int CTRL>
__device__ __forceinline__ float dpp_add_f(float x) { return x + dpp_mov_f<CTRL>(x); }
template<int CTRL>
__device__ __forceinline__ float dpp_max_f(float x) { return fmaxf(x, dpp_mov_f<CTRL>(x)); }

// ---- permlane swap helpers (VALU pipe) ----
__device__ __forceinline__ float xor32add_f(float x) {
#ifdef HAVE_PL32
    unsigned u = __builtin_bit_cast(unsigned, x);
    auto r = __builtin_amdgcn_permlane32_swap(u, u, false, false);
    return __builtin_bit_cast(float, (unsigned)r[0]) + __builtin_bit_cast(float, (unsigned)r[1]);
#else
    return x + __shfl_xor(x, 32);
#endif
}
__device__ __forceinline__ float xor32max_f(float x) {
#ifdef HAVE_PL32
    unsigned u = __builtin_bit_cast(unsigned, x);
    auto r = __builtin_amdgcn_permlane32_swap(u, u, false, false);
    return fmaxf(__builtin_bit_cast(float, (unsigned)r[0]), __builtin_bit_cast(float, (unsigned)r[1]));
#else
    return fmaxf(x, __shfl_xor(x, 32));
#endif
}
__device__ __forceinline__ float xor16add_f(float x) {
#ifdef HAVE_PL16
    unsigned u = __builtin_bit_cast(unsigned, x);
    auto r = __builtin_amdgcn_permlane16_swap(u, u, false, false);
    return __builtin_bit_cast(float, (unsigned)r[0]) + __builtin_bit_cast(float, (unsigned)r[1]);
#else
    return x + __shfl_xor(x, 16);
#endif
}
__device__ __forceinline__ float xor16max_f(float x) {
#ifdef HAVE_PL16
    unsigned u = __builtin_bit_cast(unsigned, x);
    auto r = __builtin_amdgcn_permlane16_swap(u, u, false, false);
    return fmaxf(__builtin_bit_cast(float, (unsigned)r[0]), __builtin_bit_cast(float, (unsigned)r[1]));
#else
    return fmaxf(x, __shfl_xor(x, 16));
#endif
}
__device__ __forceinline__ half2v xor32add_h2(half2v x) {
#ifdef HAVE_PL32
    unsigned u = __builtin_bit_cast(unsigned, x);
    auto r = __builtin_amdgcn_permlane32_swap(u, u, false, false);
    return h2bits((int)r[0]) + h2bits((int)r[1]);
#else
    return x + h2bits(__shfl_xor(__builtin_bit_cast(int, x), 32));
#endif
}
__device__ __forceinline__ half2v xor16add_h2(half2v x) {
#ifdef HAVE_PL16
    unsigned u = __builtin_bit_cast(unsigned, x);
    auto r = __builtin_amdgcn_permlane16_swap(u, u, false, false);
    return h2bits((int)r[0]) + h2bits((int)r[1]);
#else
    return x + h2bits(__shfl_xor(__builtin_bit_cast(int, x), 16));
#endif
}
__device__ __forceinline__ half2v xor8add_h2(half2v x) {
    return x + h2bits(__shfl_xor(__builtin_bit_cast(int, x), 8));
}

// ---- prepass: f32 -> f16 for k and v only (12 MB streamed) ----
__global__ __launch_bounds__(256) void cvt_f32_f16(
    const float* __restrict__ k, const float* __restrict__ v,
    __half* __restrict__ kh, __half* __restrict__ vh)
{
    const int i = (blockIdx.x * 256 + threadIdx.x) * 8;
    const float* src = (blockIdx.y == 0) ? k : v;
    __half*      dst = (blockIdx.y == 0) ? kh : vh;
    const float4 a = *reinterpret_cast<const float4*>(src + i);
    const float4 b = *reinterpret_cast<const float4*>(src + i + 4);
    __half2 hh[4];
    hh[0] = __float22half2_rn(make_float2(a.x, a.y));
    hh[1] = __float22half2_rn(make_float2(a.z, a.w));
    hh[2] = __float22half2_rn(make_float2(b.x, b.y));
    hh[3] = __float22half2_rn(make_float2(b.z, b.w));
    *reinterpret_cast<float4*>(dst + i) = *reinterpret_cast<const float4*>(hh);
}

// ---- main: fp16 k/v gathers in registers, XCD-head affinity ----
// grp = lane>>3 (row-group), sub = lane&7 (8-channel slice).
// Entry i <-> neighbor n = grp*8 + i: idx/etype arrive as 2+2 broadcast int4
// loads; per-entry values uniform across each group's 8 lanes, which
// legalizes the mirror-style DPP combiners. K AND V gathers issue together
// up front (16 independent loads in flight). All reduces on VALU
// (DPP/permlane) except PV's exact-xor8 (4 DS ops).
// This kernel sits at the TA address-processing floor for fp16:
// ~49 cyc/gather-instruction x 16 instructions x 64 waves/CU ~= 20 us.
__global__ __launch_bounds__(256) void wayfinder_attn_f16(
    const float* __restrict__ q,
    const __half* __restrict__ kh,
    const __half* __restrict__ vh,
    const float* __restrict__ eb,
    const int*   __restrict__ nidx,
    const int*   __restrict__ etyp,
    float* __restrict__ out)
{
    const int wave = threadIdx.x >> 6;
    const int lane = threadIdx.x & 63;
    const int bid  = blockIdx.x;
    const int work = ((bid & 7) << 9) | (bid >> 3);   // XCD i <-> head i
    const int flat = (work << 2) + wave;              // h*T + t
    const int h    = flat >> 11;
    const int t    = flat & (T - 1);
    const int grp  = lane >> 3;
    const int sub  = lane & 7;

    const long long rowoff = (long long)flat * DH;
    const int*      nrow   = nidx + (long long)flat * D;
    const int*      erow   = etyp + (long long)flat * D;

    // metadata: entries grp*8 .. grp*8+7 via broadcast int4 loads (4 VMEM)
    const int4 i0 = *reinterpret_cast<const int4*>(nrow + grp * 8);
    const int4 i1 = *reinterpret_cast<const int4*>(nrow + grp * 8 + 4);
    const int4 e0 = *reinterpret_cast<const int4*>(erow + grp * 8);
    const int4 e1 = *reinterpret_cast<const int4*>(erow + grp * 8 + 4);

    // q fragment: channels sub*8 .. sub*8+7, f32 load then in-register fp16
    const float4 qa = *reinterpret_cast<const float4*>(q + rowoff + sub * 8);
    const float4 qb = *reinterpret_cast<const float4*>(q + rowoff + sub * 8 + 4);

    const int idx_i[8] = {i0.x, i0.y, i0.z, i0.w, i1.x, i1.y, i1.z, i1.w};
    const int et_i [8] = {e0.x, e0.y, e0.z, e0.w, e1.x, e1.y, e1.z, e1.w};

    const __half* khead = kh + (long long)h * T * DH;
    const __half* vhead = vh + (long long)h * T * DH;

    // clamped rows + packed mask bits
    int s_i[8];
    int mskbits = 0;
    #pragma unroll
    for (int i = 0; i < 8; ++i) {
        s_i[i] = min(max(idx_i[i], 0), T - 1);
        mskbits |= ((idx_i[i] >= 0) && (idx_i[i] <= t)) ? (1 << i) : 0;
    }

    // K and V gathers together: one dwordx4 = full fp16 row per 8-lane group
    float4 kf[8], vf[8];
    #pragma unroll
    for (int i = 0; i < 8; ++i) {
        const long long ro = (long long)s_i[i] * DH + sub * 8;
        kf[i] = *reinterpret_cast<const float4*>(khead + ro);
        vf[i] = *reinterpret_cast<const float4*>(vhead + ro);
    }

    const float4 ebv = *reinterpret_cast<const float4*>(eb);
    float bias_i[8];
    #pragma unroll
    for (int i = 0; i < 8; ++i) {
        const int et = et_i[i];
        bias_i[i] = (et == 1) ? ebv.x : (et == 2) ? ebv.y :
                    (et == 3) ? ebv.z : (et == 4) ? ebv.w : 0.0f;
    }

    half2v qp[4];
    qp[0] = f2h2(qa.x, qa.y);
    qp[1] = f2h2(qa.z, qa.w);
    qp[2] = f2h2(qb.x, qb.y);
    qp[3] = f2h2(qb.z, qb.w);

    // QK: 4 fdot2 per row + 3 DPP-VALU reduce levels (no DS)
    float sc[8];
    #pragma unroll
    for (int i = 0; i < 8; ++i) {
        const half2v* kp = reinterpret_cast<const half2v*>(&kf[i]);
        float p = dot2acc(qp[0], kp[0],
                  dot2acc(qp[1], kp[1],
                  dot2acc(qp[2], kp[2],
                  dot2acc(qp[3], kp[3], 0.0f))));
        p = dpp_add_f<0xB1>(p);    // xor1 (exact)
        p = dpp_add_f<0x4E>(p);    // xor2 (exact)
        p = dpp_add_f<0x141>(p);   // cross-quad (quad-uniform by now)
        sc[i] = p;
    }

    // masked softmax: local over 8 entries (group-uniform), then
    // row_mirror (xor8-level) + permlane16/32 — all VALU
    float masked[8];
    float mx = -1e30f;
    #pragma unroll
    for (int i = 0; i < 8; ++i) {
        const bool mk = (mskbits >> i) & 1;
        masked[i] = mk ? fmaf(sc[i], 0.125f, bias_i[i]) : -1e30f;
        mx = fmaxf(mx, masked[i]);
    }
    mx = dpp_max_f<0x140>(mx);
    mx = xor16max_f(mx);
    mx = xor32max_f(mx);

    float e[8];
    float sum = 0.0f;
    #pragma unroll
    for (int i = 0; i < 8; ++i) {
        const bool mk = (mskbits >> i) & 1;
        e[i] = mk ? __expf(masked[i] - mx) : 0.0f;
        sum += e[i];
    }
    sum = dpp_add_f<0x140>(sum);
    sum = xor16add_f(sum);
    sum = xor32add_f(sum);
    const float rden = 1.0f / fmaxf(sum, 1e-9f);

    // PV in f32 from registers (weights already in this layout)
    float acc[8] = {0.f, 0.f, 0.f, 0.f, 0.f, 0.f, 0.f, 0.f};
    #pragma unroll
    for (int i = 0; i < 8; ++i) {
        const float w = e[i] * rden;
        const half2v* vp = reinterpret_cast<const half2v*>(&vf[i]);
        acc[0] += w * (float)vp[0].x;  acc[1] += w * (float)vp[0].y;
        acc[2] += w * (float)vp[1].x;  acc[3] += w * (float)vp[1].y;
        acc[4] += w * (float)vp[2].x;  acc[5] += w * (float)vp[2].y;
        acc[6] += w * (float)vp[3].x;  acc[7] += w * (float)vp[3].y;
    }

    // cross-group reduce on packed halves: exact xor8 (DS) then permlane
    half2v h0 = f2h2(acc[0], acc[1]);
    half2v h1 = f2h2(acc[2], acc[3]);
    half2v h2 = f2h2(acc[4], acc[5]);
    half2v h3 = f2h2(acc[6], acc[7]);
    h0 = xor8add_h2(h0);  h1 = xor8add_h2(h1);
    h2 = xor8add_h2(h2);  h3 = xor8add_h2(h3);
    h0 = xor16add_h2(h0); h1 = xor16add_h2(h1);
    h2 = xor16add_h2(h2); h3 = xor16add_h2(h3);
    h0 = xor32add_h2(h0); h1 = xor32add_h2(h1);
    h2 = xor32add_h2(h2); h3 = xor32add_h2(h3);

    if (lane < 16) {
        const int s8   = (lane & 7) * 8;
        const int half = lane >> 3;
        const float4 o = half
            ? make_float4((float)h2.x, (float)h2.y, (float)h3.x, (float)h3.y)
            : make_float4((float)h0.x, (float)h0.y, (float)h1.x, (float)h1.y);
        *reinterpret_cast<float4*>(out + rowoff + s8 + half * 4) = o;
    }
}

// ---- fallback: f32 kernel (used if ws too small) ----
__global__ __launch_bounds__(256) void wayfinder_attn_f32(
    const float* __restrict__ q, const float* __restrict__ k,
    const float* __restrict__ v, const float* __restrict__ eb,
    const int* __restrict__ nidx, const int* __restrict__ etyp,
    float* __restrict__ out)
{
    const int wave = threadIdx.x >> 6;
    const int lane = threadIdx.x & 63;
    const int flat = (blockIdx.x << 2) + wave;
    const int h    = flat >> 11;
    const int t    = flat & (T - 1);
    const int grp  = lane >> 4;
    const int sub  = lane & 15;

    __shared__ int    sidx[4][64];
    __shared__ float  ssc [4][64];
    __shared__ float2 swv [4][64];

    const long long rowoff = (long long)flat * DH;
    const long long noff = (long long)flat * D + lane;
    const int  idx = nidx[noff];
    const int  et  = etyp[noff];
    const int  s   = min(max(idx, 0), T - 1);
    const bool msk = (idx >= 0) && (idx <= t);
    const float4 ebv  = *reinterpret_cast<const float4*>(eb);
    const float  bias = (et == 1) ? ebv.x : (et == 2) ? ebv.y :
                        (et == 3) ? ebv.z : (et == 4) ? ebv.w : 0.0f;
    sidx[wave][lane] = s;
    const float4 qf = *reinterpret_cast<const float4*>(q + rowoff + sub * 4);
    __syncthreads();

    const float* khead = k + (long long)h * T * DH;
    #pragma unroll
    for (int i = 0; i < 16; ++i) {
        const int n  = i * 4 + grp;
        const int sn = sidx[wave][n];
        const float4 kf = *reinterpret_cast<const float4*>(khead + sn * DH + sub * 4);
        float p = qf.x * kf.x + qf.y * kf.y + qf.z * kf.z + qf.w * kf.w;
        p += __shfl_xor(p, 1);
        p += __shfl_xor(p, 2);
        p += __shfl_xor(p, 4);
        p += __shfl_xor(p, 8);
        if (sub == 0) ssc[wave][n] = p;
    }
    __syncthreads();

    const float sc     = ssc[wave][lane];
    const float masked = msk ? (sc * 0.125f + bias) : -1e30f;
    float mx = masked;
    #pragma unroll
    for (int off = 32; off > 0; off >>= 1) mx = fmaxf(mx, __shfl_xor(mx, off));
    const float e = msk ? __expf(masked - mx) : 0.0f;
    float sum = e;
    #pragma unroll
    for (int off = 32; off > 0; off >>= 1) sum += __shfl_xor(sum, off);
    const float w = e / fmaxf(sum, 1e-9f);
    swv[wave][lane] = make_float2(w, __int_as_float(s));
    __syncthreads();

    const float* vhead = v + (long long)h * T * DH;
    float4 acc = make_float4(0.f, 0.f, 0.f, 0.f);
    #pragma unroll
    for (int i = 0; i < 16; ++i) {
        const int    n  = i * 4 + grp;
        const float2 ws = swv[wave][n];
        const int    sn = __float_as_int(ws.y);
        const float4 vf = *reinterpret_cast<const float4*>(vhead + sn * DH + sub * 4);
        acc.x += ws.x * vf.x; acc.y += ws.x * vf.y;
        acc.z += ws.x * vf.z; acc.w += ws.x * vf.w;
    }
    #pragma unroll
    for (int off = 16; off <= 32; off <<= 1) {
        acc.x += __shfl_xor(acc.x, off); acc.y += __shfl_xor(acc.y, off);
        acc.z += __shfl_xor(acc.z, off); acc.w += __shfl_xor(acc.w, off);
    }
    if (lane < 16)
        *reinterpret_cast<float4*>(out + rowoff + sub * 4) = acc;
}

extern "C" void kernel_launch(void* const* d_in, const int* in_sizes, int n_in,
                              void* d_out, int out_size, void* d_ws, size_t ws_size,
                              hipStream_t stream) {
    const float* q    = (const float*)d_in[0];
    const float* k    = (const float*)d_in[1];
    const float* v    = (const float*)d_in[2];
    const float* eb   = (const float*)d_in[3];
    const int*   nidx = (const int*)d_in[4];
    const int*   etyp = (const int*)d_in[5];
    float* out = (float*)d_out;

    const size_t need = (size_t)2 * NKV * sizeof(__half);   // 4 MB
    if (ws_size >= need) {
        __half* kh = (__half*)d_ws;
        __half* vh = kh + NKV;
        dim3 cgrid(NKV / (256 * 8), 2);
        hipLaunchKernelGGL(cvt_f32_f16, cgrid, dim3(256), 0, stream, k, v, kh, vh);
        hipLaunchKernelGGL(wayfinder_attn_f16, dim3(H * T / 4), dim3(256), 0, stream,
                           q, kh, vh, eb, nidx, etyp, out);
    } else {
        hipLaunchKernelGGL(wayfinder_attn_f32, dim3(H * T / 4), dim3(256), 0, stream,
                           q, k, v, eb, nidx, etyp, out);
    }
}